// Round 9
// baseline (371.476 us; speedup 1.0000x reference)
//
#include <hip/hip_runtime.h>
#include <hip/hip_bf16.h>
#include <math.h>

#define HH 128
#define WW 128
#define HW 16384
#define NL 49152        // 3 * H * W lines
#define CC 128
#define NPTS0 32
#define NPTS1 8
#define PI_F 3.14159265358979323846f

typedef __attribute__((ext_vector_type(8))) short short8;
typedef __attribute__((ext_vector_type(4))) float f32x4;

__device__ __forceinline__ ushort f2bf(float f) {
    unsigned u = __builtin_bit_cast(unsigned, f);
    unsigned rounding = 0x7FFFu + ((u >> 16) & 1u);
    return (ushort)((u + rounding) >> 16);
}

__device__ __forceinline__ void gload_lds16(const void* gsrc, void* ldst) {
    __builtin_amdgcn_global_load_lds(
        (const __attribute__((address_space(1))) unsigned int*)gsrc,
        (__attribute__((address_space(3))) unsigned int*)ldst,
        16, 0, 0);
}

__device__ __forceinline__ void unpk8(uint4 d, float* f) {
    f[0] = __builtin_bit_cast(float, d.x << 16);
    f[1] = __builtin_bit_cast(float, d.x & 0xFFFF0000u);
    f[2] = __builtin_bit_cast(float, d.y << 16);
    f[3] = __builtin_bit_cast(float, d.y & 0xFFFF0000u);
    f[4] = __builtin_bit_cast(float, d.z << 16);
    f[5] = __builtin_bit_cast(float, d.z & 0xFFFF0000u);
    f[6] = __builtin_bit_cast(float, d.w << 16);
    f[7] = __builtin_bit_cast(float, d.w & 0xFFFF0000u);
}

// ---------------------------------------------------------------- lines
__global__ __launch_bounds__(256) void k_lines(
    const float* __restrict__ md, const float* __restrict__ dis,
    const float* __restrict__ res, float* __restrict__ lines)
{
    int g = blockIdx.x * 256 + threadIdx.x;
    if (g >= NL) return;
    int s = g / HW;              // 0,1,2 -> scale -1,0,1
    int pix = g - s * HW;
    float sf = (float)(s - 1);
    int y = pix >> 7, x = pix & 127;

    float md0 = md[pix], md1 = md[HW + pix], md2 = md[2 * HW + pix];
    float d = (dis[pix] + sf * res[pix]) * 5.0f;

    float md_ = (md0 - 0.5f) * (2.0f * PI_F);
    float st_ = md1 * (0.5f * PI_F);
    float ed_ = -md2 * (0.5f * PI_F);
    float cs_md = cosf(md_), ss_md = sinf(md_);
    float cs_st = fmaxf(cosf(st_), 0.001f);
    float ss_st = fmaxf(sinf(st_), 0.001f);
    float cs_ed = fmaxf(cosf(ed_), 0.001f);
    float ss_ed = fminf(sinf(ed_), -0.001f);
    float y_st = ss_st / cs_st;
    float y_ed = ss_ed / cs_ed;
    float x_st = (cs_md - ss_md * y_st) * d;
    float y_s  = (ss_md + cs_md * y_st) * d;
    float x_ed = (cs_md - ss_md * y_ed) * d;
    float y_e  = (ss_md + cs_md * y_ed) * d;

    float4 o;
    o.x = fminf(fmaxf(x_st + (float)x, 0.0f), 127.0f);
    o.y = fminf(fmaxf(y_s  + (float)y, 0.0f), 127.0f);
    o.z = fminf(fmaxf(x_ed + (float)x, 0.0f), 127.0f);
    o.w = fminf(fmaxf(y_e  + (float)y, 0.0f), 127.0f);
    ((float4*)lines)[g] = o;
}

// ---------------------------------- feats (C,HW) f32 -> (HW,C) bf16
__global__ void k_transpose(const float* __restrict__ in, ushort* __restrict__ out)
{
    __shared__ float tile[32][33];
    int cb = blockIdx.x;   // over C/32
    int pb = blockIdx.y;   // over HW/32
    int tx = threadIdx.x, ty = threadIdx.y;
#pragma unroll
    for (int j = 0; j < 32; j += 8)
        tile[ty + j][tx] = in[(size_t)(cb * 32 + ty + j) * HW + pb * 32 + tx];
    __syncthreads();
#pragma unroll
    for (int j = 0; j < 32; j += 8)
        out[(size_t)(pb * 32 + ty + j) * CC + cb * 32 + tx] = f2bf(tile[tx][ty + j]);
}

// ---------------------------------------------------------------- W -> bf16
__global__ void k_cvt(const float* __restrict__ a, const float* __restrict__ b,
                      ushort* __restrict__ oa, ushort* __restrict__ ob, int n)
{
    int i = blockIdx.x * 256 + threadIdx.x;
    if (i < n) { oa[i] = f2bf(a[i]); ob[i] = f2bf(b[i]); }
}

// ---------------------------------------------------------------- pooling
// block = 128 threads = 8 lines x 16 channel-groups-of-8.
__global__ __launch_bounds__(128, 4) void k_pool(
    const ushort* __restrict__ ft, const float* __restrict__ lines,
    ushort* __restrict__ X)
{
    __shared__ __align__(16) unsigned smeta[2048];   // 8 lines * 32 samples * 8 dwords
    const int t = threadIdx.x;
    const int l_loc = t >> 4, c8 = t & 15;
    const int gl0 = blockIdx.x * 8;

    // ---- phase A: per-(line,sample) meta, computed exactly once (2/thread)
#pragma unroll
    for (int e = 0; e < 2; ++e) {
        int s = t + e * 128;
        int ml = s >> 5, sp = s & 31;
        float4 L = ((const float4*)lines)[gl0 + ml];
        float tf = (float)sp * (1.0f / 31.0f);
        float omt = 1.0f - tf;
        float px = L.x * tf + L.z * omt - 0.5f;
        float py = L.y * tf + L.w * omt - 0.5f;
        float px0 = fminf(fmaxf(floorf(px), 0.0f), 127.0f);
        float py0 = fminf(fmaxf(floorf(py), 0.0f), 127.0f);
        float px1 = fminf(px0 + 1.0f, 127.0f);
        float py1 = fminf(py0 + 1.0f, 127.0f);
        int ix0 = (int)px0, iy0 = (int)py0, ix1 = (int)px1, iy1 = (int)py1;
        float4 wv;
        wv.x = (py1 - py) * (px1 - px);   // w00 (y0,x0)
        wv.y = (py  - py0) * (px1 - px);  // w10 (y1,x0)
        wv.z = (py1 - py) * (px  - px0);  // w01 (y0,x1)
        wv.w = (py  - py0) * (px  - px0); // w11 (y1,x1)
        int o00 = (iy0 * WW + ix0) * (CC * 2);
        int dx  = (ix1 - ix0) * (CC * 2);
        int dy  = (iy1 - iy0) * (WW * CC * 2);
        int4 ov;
        ov.x = o00;            // (y0,x0)
        ov.y = o00 + dy;       // (y1,x0)
        ov.z = o00 + dx;       // (y0,x1)
        ov.w = o00 + dy + dx;  // (y1,x1)
        *(float4*)&smeta[s * 8]     = wv;
        *(int4*)  &smeta[s * 8 + 4] = ov;
    }
    __syncthreads();

    // ---- phase B: gather (16B) + bilinear + max-pool
    const unsigned coff = (unsigned)(c8 * 16);
    const char* fbase = (const char*)ft;
    float m[8][8];
#pragma unroll
    for (int ch = 0; ch < 8; ++ch)
#pragma unroll
        for (int g = 0; g < 8; ++g) m[ch][g] = -INFINITY;

#pragma unroll
    for (int g = 0; g < 8; ++g) {
#pragma unroll
        for (int j = 0; j < 4; ++j) {
            const unsigned* mp = &smeta[(l_loc * 32 + g * 4 + j) * 8];
            float4 wv = *(const float4*)mp;
            int4  ov = *(const int4*)(mp + 4);
            uint4 d00 = *(const uint4*)(fbase + ((unsigned)ov.x + coff));
            uint4 d10 = *(const uint4*)(fbase + ((unsigned)ov.y + coff));
            uint4 d01 = *(const uint4*)(fbase + ((unsigned)ov.z + coff));
            uint4 d11 = *(const uint4*)(fbase + ((unsigned)ov.w + coff));
            float f00[8], f10[8], f01[8], f11[8];
            unpk8(d00, f00); unpk8(d10, f10); unpk8(d01, f01); unpk8(d11, f11);
#pragma unroll
            for (int ch = 0; ch < 8; ++ch) {
                float v = f00[ch] * wv.x + f10[ch] * wv.y
                        + f01[ch] * wv.z + f11[ch] * wv.w;
                m[ch][g] = fmaxf(m[ch][g], v);
            }
        }
    }

    ushort* Xp = X + (size_t)(gl0 + l_loc) * 1024 + c8 * 64;
#pragma unroll
    for (int ch = 0; ch < 8; ++ch) {
        short8 pk;
#pragma unroll
        for (int g = 0; g < 8; ++g) pk[g] = (short)f2bf(m[ch][g]);
        *(short8*)(Xp + ch * 8) = pk;
    }
}

// ---------------------------------------------------------------- GEMM 256x256
// Anti-phase wave scheduling: odd waves run their two read+MFMA clusters in
// reverse order, so half the waves MFMA while the other half issue ds_reads.
// 4-slot LDS ring, BOTH stages at distance 2, vmcnt(4), ONE barrier/K-tile.
// Slot safety: iter u stages slot (u+2)&3 only; readers touch u&3; the
// end-of-iteration barrier bounds wave drift to within one iteration.
// SWAPPED-OPERAND MFMA layout: lane l -> row = rbase+(l&15), cols j-quad.
#define NT 32            // K / 32
template<int EPI>
__global__ __launch_bounds__(512, 2) void k_gemm2(
    const ushort* __restrict__ A, const ushort* __restrict__ B,
    const float* __restrict__ bias, ushort* __restrict__ Y,
    const float* __restrict__ w3, float* __restrict__ logits,
    int M, int N, int K)
{
    __shared__ __align__(16) ushort lds[65536];   // A: [0,32768), B: [32768,65536)
    const int tid = threadIdx.x;
    const int w = tid >> 6, l = tid & 63;
    const int lr = l & 15, kq = l >> 4;
    const int wm = w >> 2, wn = w & 3;

    // T1: bijective XCD swizzle (gridDim.x % 8 == 0)
    const int nwg = gridDim.x;
    const int cpx = nwg >> 3;
    const int swz = (blockIdx.x & 7) * cpx + (blockIdx.x >> 3);
    const int nbm = M >> 8;
    const int m_blk = swz % nbm;
    const int n_blk = swz / nbm;
    const int m0 = m_blk << 8, n0 = n_blk << 8;

    // staging source precompute (T2 inverse swizzle on source granule)
    const int G0 = tid, G1 = 512 + tid;
    const int r0 = G0 >> 2, r1 = G1 >> 2;
    const int g0 = (G0 & 3) ^ ((r0 >> 1) & 3);
    const int g1 = (G1 & 3) ^ ((r1 >> 1) & 3);
    const ushort* sA0 = A + (size_t)(m0 + r0) * K + g0 * 8;
    const ushort* sA1 = A + (size_t)(m0 + r1) * K + g1 * 8;
    const ushort* sB0 = B + (size_t)(n0 + r0) * K + g0 * 8;
    const ushort* sB1 = B + (size_t)(n0 + r1) * K + g1 * 8;
    ushort* dA0 = &lds[G0 * 8];
    ushort* dA1 = &lds[G1 * 8];
    ushort* dB0 = &lds[32768 + G0 * 8];
    ushort* dB1 = &lds[32768 + G1 * 8];

#define STAGE_A(tp) { int sb_ = ((tp) & 3) * 8192; \
    gload_lds16(sA0 + (tp) * 32, dA0 + sb_); \
    gload_lds16(sA1 + (tp) * 32, dA1 + sb_); }
#define STAGE_B(tp) { int sb_ = ((tp) & 3) * 8192; \
    gload_lds16(sB0 + (tp) * 32, dB0 + sb_); \
    gload_lds16(sB1 + (tp) * 32, dB1 + sb_); }
#define SBAR  { __builtin_amdgcn_sched_barrier(0); __builtin_amdgcn_s_barrier(); \
                __builtin_amdgcn_sched_barrier(0); }

    // swizzled ds_read offsets (ushort units)
    int aidx[8], bidx[4];
#pragma unroll
    for (int m = 0; m < 8; ++m) {
        int r = wm * 128 + m * 16 + lr;
        int g = kq ^ ((r >> 1) & 3);
        aidx[m] = r * 32 + g * 8;
    }
#pragma unroll
    for (int n = 0; n < 4; ++n) {
        int r = wn * 64 + n * 16 + lr;
        int g = kq ^ ((r >> 1) & 3);
        bidx[n] = 32768 + r * 32 + g * 8;
    }

    f32x4 acc[8][4] = {};
    const bool wodd = (w & 1) != 0;

    // prologue: stage tiles 0 and 1 (8 loads); tile0 ready after vmcnt(4)
    STAGE_A(0); STAGE_B(0); STAGE_A(1); STAGE_B(1);
    asm volatile("s_waitcnt vmcnt(4)" ::: "memory");
    SBAR;

#define CLUSTER(mlo) { \
    short8 am0 = *(const short8*)&lds[sb + aidx[(mlo)]];     \
    short8 am1 = *(const short8*)&lds[sb + aidx[(mlo) + 1]]; \
    short8 am2 = *(const short8*)&lds[sb + aidx[(mlo) + 2]]; \
    short8 am3 = *(const short8*)&lds[sb + aidx[(mlo) + 3]]; \
    __builtin_amdgcn_s_setprio(1);                            \
    acc[(mlo)][0]   = __builtin_amdgcn_mfma_f32_16x16x32_bf16(bq0, am0, acc[(mlo)][0], 0, 0, 0);   \
    acc[(mlo)][1]   = __builtin_amdgcn_mfma_f32_16x16x32_bf16(bq1, am0, acc[(mlo)][1], 0, 0, 0);   \
    acc[(mlo)][2]   = __builtin_amdgcn_mfma_f32_16x16x32_bf16(bq2, am0, acc[(mlo)][2], 0, 0, 0);   \
    acc[(mlo)][3]   = __builtin_amdgcn_mfma_f32_16x16x32_bf16(bq3, am0, acc[(mlo)][3], 0, 0, 0);   \
    acc[(mlo)+1][0] = __builtin_amdgcn_mfma_f32_16x16x32_bf16(bq0, am1, acc[(mlo)+1][0], 0, 0, 0); \
    acc[(mlo)+1][1] = __builtin_amdgcn_mfma_f32_16x16x32_bf16(bq1, am1, acc[(mlo)+1][1], 0, 0, 0); \
    acc[(mlo)+1][2] = __builtin_amdgcn_mfma_f32_16x16x32_bf16(bq2, am1, acc[(mlo)+1][2], 0, 0, 0); \
    acc[(mlo)+1][3] = __builtin_amdgcn_mfma_f32_16x16x32_bf16(bq3, am1, acc[(mlo)+1][3], 0, 0, 0); \
    acc[(mlo)+2][0] = __builtin_amdgcn_mfma_f32_16x16x32_bf16(bq0, am2, acc[(mlo)+2][0], 0, 0, 0); \
    acc[(mlo)+2][1] = __builtin_amdgcn_mfma_f32_16x16x32_bf16(bq1, am2, acc[(mlo)+2][1], 0, 0, 0); \
    acc[(mlo)+2][2] = __builtin_amdgcn_mfma_f32_16x16x32_bf16(bq2, am2, acc[(mlo)+2][2], 0, 0, 0); \
    acc[(mlo)+2][3] = __builtin_amdgcn_mfma_f32_16x16x32_bf16(bq3, am2, acc[(mlo)+2][3], 0, 0, 0); \
    acc[(mlo)+3][0] = __builtin_amdgcn_mfma_f32_16x16x32_bf16(bq0, am3, acc[(mlo)+3][0], 0, 0, 0); \
    acc[(mlo)+3][1] = __builtin_amdgcn_mfma_f32_16x16x32_bf16(bq1, am3, acc[(mlo)+3][1], 0, 0, 0); \
    acc[(mlo)+3][2] = __builtin_amdgcn_mfma_f32_16x16x32_bf16(bq2, am3, acc[(mlo)+3][2], 0, 0, 0); \
    acc[(mlo)+3][3] = __builtin_amdgcn_mfma_f32_16x16x32_bf16(bq3, am3, acc[(mlo)+3][3], 0, 0, 0); \
    __builtin_amdgcn_s_setprio(0); }

    for (int t = 0; t < NT; ++t) {
        const int sb = (t & 3) * 8192;
        short8 bq0 = *(const short8*)&lds[sb + bidx[0]];
        short8 bq1 = *(const short8*)&lds[sb + bidx[1]];
        short8 bq2 = *(const short8*)&lds[sb + bidx[2]];
        short8 bq3 = *(const short8*)&lds[sb + bidx[3]];
        if (wodd) {
            CLUSTER(4)
            if (t + 2 < NT) STAGE_B(t + 2);
            CLUSTER(0)
            if (t + 2 < NT) STAGE_A(t + 2);
        } else {
            CLUSTER(0)
            if (t + 2 < NT) STAGE_B(t + 2);
            CLUSTER(4)
            if (t + 2 < NT) STAGE_A(t + 2);
        }
        if (t < NT - 2) {
            asm volatile("s_waitcnt vmcnt(4)" ::: "memory");
        } else {
            asm volatile("s_waitcnt vmcnt(0)" ::: "memory");
        }
        SBAR;
    }
#undef CLUSTER
#undef STAGE_A
#undef STAGE_B
#undef SBAR

    // ---------------- epilogue (swapped layout: row = rbase+lr, cols j-quad)
    if (EPI == 0) {
#pragma unroll
        for (int n = 0; n < 4; ++n) {
            int cbase = n0 + wn * 64 + n * 16 + kq * 4;
            float4 bv4 = *(const float4*)&bias[cbase];
#pragma unroll
            for (int m = 0; m < 8; ++m) {
                int row = m0 + wm * 128 + m * 16 + lr;
                ushort4 pk;
                pk.x = f2bf(fmaxf(acc[m][n][0] + bv4.x, 0.0f));
                pk.y = f2bf(fmaxf(acc[m][n][1] + bv4.y, 0.0f));
                pk.z = f2bf(fmaxf(acc[m][n][2] + bv4.z, 0.0f));
                pk.w = f2bf(fmaxf(acc[m][n][3] + bv4.w, 0.0f));
                *(ushort4*)(Y + (size_t)row * N + cbase) = pk;
            }
        }
    } else {
        float4 bv4[4], w34[4];
#pragma unroll
        for (int n = 0; n < 4; ++n) {
            int cbase = n0 + wn * 64 + n * 16 + kq * 4;
            bv4[n] = *(const float4*)&bias[cbase];
            w34[n] = *(const float4*)&w3[cbase];
        }
#pragma unroll
        for (int m = 0; m < 8; ++m) {
            float s = 0.0f;
#pragma unroll
            for (int n = 0; n < 4; ++n) {
                s += fmaxf(acc[m][n][0] + bv4[n].x, 0.0f) * w34[n].x;
                s += fmaxf(acc[m][n][1] + bv4[n].y, 0.0f) * w34[n].y;
                s += fmaxf(acc[m][n][2] + bv4[n].z, 0.0f) * w34[n].z;
                s += fmaxf(acc[m][n][3] + bv4[n].w, 0.0f) * w34[n].w;
            }
            s += __shfl_xor(s, 16, 64);
            s += __shfl_xor(s, 32, 64);
            if (kq == 0)
                atomicAdd(&logits[m0 + wm * 128 + m * 16 + lr], s);
        }
    }
}

// ---------------------------------------------------------------- logits = b3
__global__ void k_init_logits(float* __restrict__ logits, const float* __restrict__ b3, int n)
{
    int i = blockIdx.x * 256 + threadIdx.x;
    if (i < n) logits[i] = b3[0];
}

// --------------------------------------------- NMS + per-chunk top-50
__global__ __launch_bounds__(256) void k_nms_topk(
    const float* __restrict__ jloc, unsigned long long* __restrict__ cand)
{
    __shared__ unsigned long long sk[256];
    const int t = threadIdx.x;
    const int idx = blockIdx.x * 256 + t;      // 64 chunks x 2 rows
    const int y = idx >> 7, x = idx & 127;
    float cv = jloc[idx];
    float m = cv;
    for (int dy = -1; dy <= 1; ++dy) {
        int yy = y + dy;
        if (yy < 0 || yy > 127) continue;
        for (int dx = -1; dx <= 1; ++dx) {
            int xx = x + dx;
            if (xx < 0 || xx > 127) continue;
            m = fmaxf(m, jloc[(yy << 7) + xx]);
        }
    }
    float nv = (cv == m) ? cv : 0.0f;
    unsigned vb = __builtin_bit_cast(unsigned, nv);
    sk[t] = ((unsigned long long)vb << 32) | (unsigned)(0xFFFFFFFFu - idx);
    __syncthreads();
    for (int k = 2; k <= 256; k <<= 1) {
        for (int j = k >> 1; j >= 1; j >>= 1) {
            int ixj = t ^ j;
            if (ixj > t) {
                unsigned long long a = sk[t], b = sk[ixj];
                bool up = ((t & k) == 0);
                if (up ? (a < b) : (a > b)) { sk[t] = b; sk[ixj] = a; }
            }
            __syncthreads();
        }
    }
    if (t < 64) cand[blockIdx.x * 64 + t] = (t < 50) ? sk[t] : 0ull;
}

// --------------------------------------------- merge 64x50 -> top-50 + junctions
__global__ __launch_bounds__(1024) void k_topk_final(
    const unsigned long long* __restrict__ cand,
    const float* __restrict__ joff, float* __restrict__ outj)
{
    __shared__ unsigned long long sk[4096];
    const int t = threadIdx.x;
#pragma unroll
    for (int e = 0; e < 4; ++e) sk[t + (e << 10)] = cand[t + (e << 10)];
    __syncthreads();
    for (int k = 2; k <= 4096; k <<= 1) {
        for (int j = k >> 1; j >= 1; j >>= 1) {
#pragma unroll
            for (int e = 0; e < 4; ++e) {
                int i = t + (e << 10);
                int ixj = i ^ j;
                if (ixj > i) {
                    unsigned long long a = sk[i], b = sk[ixj];
                    bool up = ((i & k) == 0);
                    if (up ? (a < b) : (a > b)) { sk[i] = b; sk[ixj] = a; }
                }
            }
            __syncthreads();
        }
    }
    if (t < 50) {
        unsigned long long kk = sk[t];
        unsigned idx = 0xFFFFFFFFu - (unsigned)(kk & 0xFFFFFFFFull);
        float val = __builtin_bit_cast(float, (unsigned)(kk >> 32));
        int y = idx >> 7, x = idx & 127;
        outj[2 * t]     = (float)x + joff[idx]      + 0.5f;
        outj[2 * t + 1] = (float)y + joff[HW + idx] + 0.5f;
        outj[100 + t]   = val;
    }
}

// ---------------------------------------------------------------- launch
extern "C" void kernel_launch(void* const* d_in, const int* in_sizes, int n_in,
                              void* d_out, int out_size, void* d_ws, size_t ws_size,
                              hipStream_t stream) {
    const float* md   = (const float*)d_in[0];
    const float* dis  = (const float*)d_in[1];
    const float* res  = (const float*)d_in[2];
    const float* jloc = (const float*)d_in[3];
    const float* joff = (const float*)d_in[4];
    const float* feats= (const float*)d_in[5];
    const float* W1   = (const float*)d_in[6];
    const float* b1   = (const float*)d_in[7];
    const float* W2   = (const float*)d_in[8];
    const float* b2   = (const float*)d_in[9];
    const float* W3   = (const float*)d_in[10];
    const float* b3   = (const float*)d_in[11];
    float* out = (float*)d_out;

    char* ws = (char*)d_ws;
    size_t off = 0;
    auto alloc = [&](size_t bytes) {
        void* p = ws + off;
        off = (off + bytes + 255) & ~(size_t)255;
        return p;
    };
    float*  lines = (float*) alloc((size_t)NL * 4 * sizeof(float));
    ushort* ft    = (ushort*)alloc((size_t)HW * CC * 2);
    ushort* W1b   = (ushort*)alloc((size_t)1024 * 1024 * 2);
    ushort* W2b   = (ushort*)alloc((size_t)1024 * 1024 * 2);
    ushort* X     = (ushort*)alloc((size_t)NL * 1024 * 2);
    ushort* Y1    = (ushort*)alloc((size_t)NL * 1024 * 2);
    unsigned long long* cand = (unsigned long long*)alloc(4096 * 8);

    k_lines<<<NL / 256, 256, 0, stream>>>(md, dis, res, lines);
    k_transpose<<<dim3(CC / 32, HW / 32), dim3(32, 8), 0, stream>>>(feats, ft);
    k_cvt<<<(1024 * 1024) / 256, 256, 0, stream>>>(W1, W2, W1b, W2b, 1024 * 1024);
    k_pool<<<NL / 8, 128, 0, stream>>>(ft, lines, X);

    int ngrid = (NL / 256) * (1024 / 256);   // 768, divisible by 8
    k_gemm2<0><<<ngrid, 512, 0, stream>>>(X, W1b, b1, Y1, nullptr, nullptr, NL, 1024, 1024);
    k_init_logits<<<NL / 256, 256, 0, stream>>>(out, b3, NL);
    k_gemm2<1><<<ngrid, 512, 0, stream>>>(Y1, W2b, b2, nullptr, W3, out, NL, 1024, 1024);

    k_nms_topk<<<64, 256, 0, stream>>>(jloc, cand);
    k_topk_final<<<1, 1024, 0, stream>>>(cand, joff, out + NL);
}

// Round 10
// 352.823 us; speedup vs baseline: 1.0529x; 1.0529x over previous
//
#include <hip/hip_runtime.h>
#include <hip/hip_bf16.h>
#include <math.h>

#define HH 128
#define WW 128
#define HW 16384
#define NL 49152        // 3 * H * W lines
#define CC 128
#define NPTS0 32
#define NPTS1 8
#define PI_F 3.14159265358979323846f

typedef __attribute__((ext_vector_type(8))) short short8;
typedef __attribute__((ext_vector_type(4))) float f32x4;

__device__ __forceinline__ ushort f2bf(float f) {
    unsigned u = __builtin_bit_cast(unsigned, f);
    unsigned rounding = 0x7FFFu + ((u >> 16) & 1u);
    return (ushort)((u + rounding) >> 16);
}

__device__ __forceinline__ void gload_lds16(const void* gsrc, void* ldst) {
    __builtin_amdgcn_global_load_lds(
        (const __attribute__((address_space(1))) unsigned int*)gsrc,
        (__attribute__((address_space(3))) unsigned int*)ldst,
        16, 0, 0);
}

__device__ __forceinline__ void unpk8(uint4 d, float* f) {
    f[0] = __builtin_bit_cast(float, d.x << 16);
    f[1] = __builtin_bit_cast(float, d.x & 0xFFFF0000u);
    f[2] = __builtin_bit_cast(float, d.y << 16);
    f[3] = __builtin_bit_cast(float, d.y & 0xFFFF0000u);
    f[4] = __builtin_bit_cast(float, d.z << 16);
    f[5] = __builtin_bit_cast(float, d.z & 0xFFFF0000u);
    f[6] = __builtin_bit_cast(float, d.w << 16);
    f[7] = __builtin_bit_cast(float, d.w & 0xFFFF0000u);
}

// ---------------------------------------------------------------- lines
__global__ __launch_bounds__(256) void k_lines(
    const float* __restrict__ md, const float* __restrict__ dis,
    const float* __restrict__ res, float* __restrict__ lines)
{
    int g = blockIdx.x * 256 + threadIdx.x;
    if (g >= NL) return;
    int s = g / HW;              // 0,1,2 -> scale -1,0,1
    int pix = g - s * HW;
    float sf = (float)(s - 1);
    int y = pix >> 7, x = pix & 127;

    float md0 = md[pix], md1 = md[HW + pix], md2 = md[2 * HW + pix];
    float d = (dis[pix] + sf * res[pix]) * 5.0f;

    float md_ = (md0 - 0.5f) * (2.0f * PI_F);
    float st_ = md1 * (0.5f * PI_F);
    float ed_ = -md2 * (0.5f * PI_F);
    float cs_md = cosf(md_), ss_md = sinf(md_);
    float cs_st = fmaxf(cosf(st_), 0.001f);
    float ss_st = fmaxf(sinf(st_), 0.001f);
    float cs_ed = fmaxf(cosf(ed_), 0.001f);
    float ss_ed = fminf(sinf(ed_), -0.001f);
    float y_st = ss_st / cs_st;
    float y_ed = ss_ed / cs_ed;
    float x_st = (cs_md - ss_md * y_st) * d;
    float y_s  = (ss_md + cs_md * y_st) * d;
    float x_ed = (cs_md - ss_md * y_ed) * d;
    float y_e  = (ss_md + cs_md * y_ed) * d;

    float4 o;
    o.x = fminf(fmaxf(x_st + (float)x, 0.0f), 127.0f);
    o.y = fminf(fmaxf(y_s  + (float)y, 0.0f), 127.0f);
    o.z = fminf(fmaxf(x_ed + (float)x, 0.0f), 127.0f);
    o.w = fminf(fmaxf(y_e  + (float)y, 0.0f), 127.0f);
    ((float4*)lines)[g] = o;
}

// ---------------------------------- feats (C,HW) f32 -> (HW,C) bf16
__global__ void k_transpose(const float* __restrict__ in, ushort* __restrict__ out)
{
    __shared__ float tile[32][33];
    int cb = blockIdx.x;   // over C/32
    int pb = blockIdx.y;   // over HW/32
    int tx = threadIdx.x, ty = threadIdx.y;
#pragma unroll
    for (int j = 0; j < 32; j += 8)
        tile[ty + j][tx] = in[(size_t)(cb * 32 + ty + j) * HW + pb * 32 + tx];
    __syncthreads();
#pragma unroll
    for (int j = 0; j < 32; j += 8)
        out[(size_t)(pb * 32 + ty + j) * CC + cb * 32 + tx] = f2bf(tile[tx][ty + j]);
}

// ---------------------------------------------------------------- W -> bf16
__global__ void k_cvt(const float* __restrict__ a, const float* __restrict__ b,
                      ushort* __restrict__ oa, ushort* __restrict__ ob, int n)
{
    int i = blockIdx.x * 256 + threadIdx.x;
    if (i < n) { oa[i] = f2bf(a[i]); ob[i] = f2bf(b[i]); }
}

// ---------------------------------------------------------------- pooling
// block = 128 threads = 8 lines x 16 channel-groups-of-8.
__global__ __launch_bounds__(128, 4) void k_pool(
    const ushort* __restrict__ ft, const float* __restrict__ lines,
    ushort* __restrict__ X)
{
    __shared__ __align__(16) unsigned smeta[2048];   // 8 lines * 32 samples * 8 dwords
    const int t = threadIdx.x;
    const int l_loc = t >> 4, c8 = t & 15;
    const int gl0 = blockIdx.x * 8;

    // ---- phase A: per-(line,sample) meta, computed exactly once (2/thread)
#pragma unroll
    for (int e = 0; e < 2; ++e) {
        int s = t + e * 128;
        int ml = s >> 5, sp = s & 31;
        float4 L = ((const float4*)lines)[gl0 + ml];
        float tf = (float)sp * (1.0f / 31.0f);
        float omt = 1.0f - tf;
        float px = L.x * tf + L.z * omt - 0.5f;
        float py = L.y * tf + L.w * omt - 0.5f;
        float px0 = fminf(fmaxf(floorf(px), 0.0f), 127.0f);
        float py0 = fminf(fmaxf(floorf(py), 0.0f), 127.0f);
        float px1 = fminf(px0 + 1.0f, 127.0f);
        float py1 = fminf(py0 + 1.0f, 127.0f);
        int ix0 = (int)px0, iy0 = (int)py0, ix1 = (int)px1, iy1 = (int)py1;
        float4 wv;
        wv.x = (py1 - py) * (px1 - px);   // w00 (y0,x0)
        wv.y = (py  - py0) * (px1 - px);  // w10 (y1,x0)
        wv.z = (py1 - py) * (px  - px0);  // w01 (y0,x1)
        wv.w = (py  - py0) * (px  - px0); // w11 (y1,x1)
        int o00 = (iy0 * WW + ix0) * (CC * 2);
        int dx  = (ix1 - ix0) * (CC * 2);
        int dy  = (iy1 - iy0) * (WW * CC * 2);
        int4 ov;
        ov.x = o00;            // (y0,x0)
        ov.y = o00 + dy;       // (y1,x0)
        ov.z = o00 + dx;       // (y0,x1)
        ov.w = o00 + dy + dx;  // (y1,x1)
        *(float4*)&smeta[s * 8]     = wv;
        *(int4*)  &smeta[s * 8 + 4] = ov;
    }
    __syncthreads();

    // ---- phase B: gather (16B) + bilinear + max-pool
    const unsigned coff = (unsigned)(c8 * 16);
    const char* fbase = (const char*)ft;
    float m[8][8];
#pragma unroll
    for (int ch = 0; ch < 8; ++ch)
#pragma unroll
        for (int g = 0; g < 8; ++g) m[ch][g] = -INFINITY;

#pragma unroll
    for (int g = 0; g < 8; ++g) {
#pragma unroll
        for (int j = 0; j < 4; ++j) {
            const unsigned* mp = &smeta[(l_loc * 32 + g * 4 + j) * 8];
            float4 wv = *(const float4*)mp;
            int4  ov = *(const int4*)(mp + 4);
            uint4 d00 = *(const uint4*)(fbase + ((unsigned)ov.x + coff));
            uint4 d10 = *(const uint4*)(fbase + ((unsigned)ov.y + coff));
            uint4 d01 = *(const uint4*)(fbase + ((unsigned)ov.z + coff));
            uint4 d11 = *(const uint4*)(fbase + ((unsigned)ov.w + coff));
            float f00[8], f10[8], f01[8], f11[8];
            unpk8(d00, f00); unpk8(d10, f10); unpk8(d01, f01); unpk8(d11, f11);
#pragma unroll
            for (int ch = 0; ch < 8; ++ch) {
                float v = f00[ch] * wv.x + f10[ch] * wv.y
                        + f01[ch] * wv.z + f11[ch] * wv.w;
                m[ch][g] = fmaxf(m[ch][g], v);
            }
        }
    }

    ushort* Xp = X + (size_t)(gl0 + l_loc) * 1024 + c8 * 64;
#pragma unroll
    for (int ch = 0; ch < 8; ++ch) {
        short8 pk;
#pragma unroll
        for (int g = 0; g < 8; ++g) pk[g] = (short)f2bf(m[ch][g]);
        *(short8*)(Xp + ch * 8) = pk;
    }
}

// ---------------------------------------------------------------- GEMM 256x256
// 8-phase deep pipeline (m201 template): BK=64, 2 LDS buffers, per phase
// {ds_read subtile || stage 1 half-tile} -> barrier -> 16 MFMA -> barrier,
// counted vmcnt(2) only at phases 4 & 8. Row-XOR granule swizzle both sides.
// Region map (ushort units): A0=0, B0=16384, A1=32768, B1=49152;
// each region's halves at +0 / +8192 (128 rows x 64 cols each).
// Stage plan per iteration i (tiles 2i:buf0, 2i+1:buf1):
//  ph1:Bhi(buf1,2i+1) ph2:Alo(buf1,2i+1) ph3:Ahi(buf1,2i+1)
//  ph4:Blo(buf0,2i+2) ph5:Bhi(buf0,2i+2) ph6:Alo(buf0,2i+2) ph7:Ahi(buf0,2i+2)
//  ph8:Blo(buf1,2i+3)   [ph4-8 guarded by i<7]
// Every stage lands >=2 barriers after its region's last read; every read is
// covered by the counted vmcnt+barrier at the preceding ph4/ph8 boundary.
#define NIT 8            // iterations; each covers 2 K-tiles of 64 (K=1024)
template<int EPI>
__global__ __launch_bounds__(512, 1) void k_gemm2(
    const ushort* __restrict__ A, const ushort* __restrict__ B,
    const float* __restrict__ bias, ushort* __restrict__ Y,
    const float* __restrict__ w3, float* __restrict__ logits,
    int M, int N, int K)
{
    __shared__ __align__(16) ushort lds[65536];
    const int tid = threadIdx.x;
    const int w = tid >> 6, l = tid & 63;
    const int lr = l & 15, kq = l >> 4;
    const int wm = w >> 2, wn = w & 3;

    // T1: bijective XCD swizzle (gridDim.x % 8 == 0)
    const int nwg = gridDim.x;
    const int cpx = nwg >> 3;
    const int swzb = (blockIdx.x & 7) * cpx + (blockIdx.x >> 3);
    const int nbm = M >> 8;
    const int m_blk = swzb % nbm;
    const int n_blk = swzb / nbm;
    const int m0 = m_blk << 8, n0 = n_blk << 8;

    const ushort* pA = A + (size_t)m0 * K;
    const ushort* pB = B + (size_t)n0 * K;

    // staging: thread covers rows rS and rS+64 of a 128-row half-tile,
    // granule position tid&7; source granule inverse-swizzled.
    const int rS = tid >> 3;
    const int gS = (tid & 7) ^ (rS & 7);

#define STG(gp, rowoff, kt, regbase) { \
    gload_lds16((gp) + (size_t)((rowoff) + rS) * K + (kt) * 64 + gS * 8, \
                &lds[(regbase) + tid * 8]); \
    gload_lds16((gp) + (size_t)((rowoff) + 64 + rS) * K + (kt) * 64 + gS * 8, \
                &lds[(regbase) + 4096 + tid * 8]); }

#define FBAR { __builtin_amdgcn_sched_barrier(0); __builtin_amdgcn_s_barrier(); \
               __builtin_amdgcn_sched_barrier(0); }

    // ds_read offsets (ushort units); swizzled granule per k-sub
    const int swz0 = ((kq) ^ (lr & 7)) * 8;
    const int swz1 = ((4 + kq) ^ (lr & 7)) * 8;
    int aoff[8], boff[4];
#pragma unroll
    for (int m = 0; m < 8; ++m) aoff[m] = (wm * 128 + m * 16 + lr) * 64;
#pragma unroll
    for (int n = 0; n < 4; ++n) boff[n] = 16384 + (wn * 64 + n * 16 + lr) * 64;

    f32x4 acc[8][4] = {};
    short8 bq0, bq1, bq2, bq3;

#define MF16(MLO, A0, A1, A2, A3) \
    acc[MLO+0][0] = __builtin_amdgcn_mfma_f32_16x16x32_bf16(bq0, A0, acc[MLO+0][0], 0, 0, 0); \
    acc[MLO+0][1] = __builtin_amdgcn_mfma_f32_16x16x32_bf16(bq1, A0, acc[MLO+0][1], 0, 0, 0); \
    acc[MLO+0][2] = __builtin_amdgcn_mfma_f32_16x16x32_bf16(bq2, A0, acc[MLO+0][2], 0, 0, 0); \
    acc[MLO+0][3] = __builtin_amdgcn_mfma_f32_16x16x32_bf16(bq3, A0, acc[MLO+0][3], 0, 0, 0); \
    acc[MLO+1][0] = __builtin_amdgcn_mfma_f32_16x16x32_bf16(bq0, A1, acc[MLO+1][0], 0, 0, 0); \
    acc[MLO+1][1] = __builtin_amdgcn_mfma_f32_16x16x32_bf16(bq1, A1, acc[MLO+1][1], 0, 0, 0); \
    acc[MLO+1][2] = __builtin_amdgcn_mfma_f32_16x16x32_bf16(bq2, A1, acc[MLO+1][2], 0, 0, 0); \
    acc[MLO+1][3] = __builtin_amdgcn_mfma_f32_16x16x32_bf16(bq3, A1, acc[MLO+1][3], 0, 0, 0); \
    acc[MLO+2][0] = __builtin_amdgcn_mfma_f32_16x16x32_bf16(bq0, A2, acc[MLO+2][0], 0, 0, 0); \
    acc[MLO+2][1] = __builtin_amdgcn_mfma_f32_16x16x32_bf16(bq1, A2, acc[MLO+2][1], 0, 0, 0); \
    acc[MLO+2][2] = __builtin_amdgcn_mfma_f32_16x16x32_bf16(bq2, A2, acc[MLO+2][2], 0, 0, 0); \
    acc[MLO+2][3] = __builtin_amdgcn_mfma_f32_16x16x32_bf16(bq3, A2, acc[MLO+2][3], 0, 0, 0); \
    acc[MLO+3][0] = __builtin_amdgcn_mfma_f32_16x16x32_bf16(bq0, A3, acc[MLO+3][0], 0, 0, 0); \
    acc[MLO+3][1] = __builtin_amdgcn_mfma_f32_16x16x32_bf16(bq1, A3, acc[MLO+3][1], 0, 0, 0); \
    acc[MLO+3][2] = __builtin_amdgcn_mfma_f32_16x16x32_bf16(bq2, A3, acc[MLO+3][2], 0, 0, 0); \
    acc[MLO+3][3] = __builtin_amdgcn_mfma_f32_16x16x32_bf16(bq3, A3, acc[MLO+3][3], 0, 0, 0);

    // prologue: tile0 fully into buf0, tile1's B-lo into buf1
    STG(pA, 0,   0, 0);      // A-lo buf0
    STG(pA, 128, 0, 8192);   // A-hi buf0
    STG(pB, 0,   0, 16384);  // B-lo buf0
    STG(pB, 128, 0, 24576);  // B-hi buf0
    STG(pB, 0,   1, 49152);  // B-lo buf1
    asm volatile("s_waitcnt vmcnt(2)" ::: "memory");
    FBAR;

    for (int i = 0; i < NIT; ++i) {
        const int t1 = 2 * i + 1, t2 = 2 * i + 2, t3 = 2 * i + 3;
        const bool pf = (i < NIT - 1);

        // ---- ph1: buf0, ksub0, m0-3 (reads B + A)
        bq0 = *(const short8*)&lds[boff[0] + swz0];
        bq1 = *(const short8*)&lds[boff[1] + swz0];
        bq2 = *(const short8*)&lds[boff[2] + swz0];
        bq3 = *(const short8*)&lds[boff[3] + swz0];
        {
            short8 a0 = *(const short8*)&lds[aoff[0] + swz0];
            short8 a1 = *(const short8*)&lds[aoff[1] + swz0];
            short8 a2 = *(const short8*)&lds[aoff[2] + swz0];
            short8 a3 = *(const short8*)&lds[aoff[3] + swz0];
            STG(pB, 128, t1, 57344);   // B-hi buf1
            FBAR;
            __builtin_amdgcn_s_setprio(1); MF16(0, a0, a1, a2, a3) __builtin_amdgcn_s_setprio(0);
            FBAR;
        }
        // ---- ph2: buf0, ksub0, m4-7
        {
            short8 a4 = *(const short8*)&lds[aoff[4] + swz0];
            short8 a5 = *(const short8*)&lds[aoff[5] + swz0];
            short8 a6 = *(const short8*)&lds[aoff[6] + swz0];
            short8 a7 = *(const short8*)&lds[aoff[7] + swz0];
            STG(pA, 0, t1, 32768);     // A-lo buf1
            FBAR;
            __builtin_amdgcn_s_setprio(1); MF16(4, a4, a5, a6, a7) __builtin_amdgcn_s_setprio(0);
            FBAR;
        }
        // ---- ph3: buf0, ksub1, m0-3 (reads B + A)
        bq0 = *(const short8*)&lds[boff[0] + swz1];
        bq1 = *(const short8*)&lds[boff[1] + swz1];
        bq2 = *(const short8*)&lds[boff[2] + swz1];
        bq3 = *(const short8*)&lds[boff[3] + swz1];
        {
            short8 a0 = *(const short8*)&lds[aoff[0] + swz1];
            short8 a1 = *(const short8*)&lds[aoff[1] + swz1];
            short8 a2 = *(const short8*)&lds[aoff[2] + swz1];
            short8 a3 = *(const short8*)&lds[aoff[3] + swz1];
            STG(pA, 128, t1, 40960);   // A-hi buf1
            FBAR;
            __builtin_amdgcn_s_setprio(1); MF16(0, a0, a1, a2, a3) __builtin_amdgcn_s_setprio(0);
            FBAR;
        }
        // ---- ph4: buf0, ksub1, m4-7  + counted vmcnt
        {
            short8 a4 = *(const short8*)&lds[aoff[4] + swz1];
            short8 a5 = *(const short8*)&lds[aoff[5] + swz1];
            short8 a6 = *(const short8*)&lds[aoff[6] + swz1];
            short8 a7 = *(const short8*)&lds[aoff[7] + swz1];
            if (pf) STG(pB, 0, t2, 16384);   // B-lo buf0
            FBAR;
            __builtin_amdgcn_s_setprio(1); MF16(4, a4, a5, a6, a7) __builtin_amdgcn_s_setprio(0);
            if (pf) { asm volatile("s_waitcnt vmcnt(2)" ::: "memory"); }
            else    { asm volatile("s_waitcnt vmcnt(0)" ::: "memory"); }
            FBAR;
        }
        // ---- ph5: buf1, ksub0, m0-3 (reads B + A)
        bq0 = *(const short8*)&lds[32768 + boff[0] + swz0];
        bq1 = *(const short8*)&lds[32768 + boff[1] + swz0];
        bq2 = *(const short8*)&lds[32768 + boff[2] + swz0];
        bq3 = *(const short8*)&lds[32768 + boff[3] + swz0];
        {
            short8 a0 = *(const short8*)&lds[32768 + aoff[0] + swz0];
            short8 a1 = *(const short8*)&lds[32768 + aoff[1] + swz0];
            short8 a2 = *(const short8*)&lds[32768 + aoff[2] + swz0];
            short8 a3 = *(const short8*)&lds[32768 + aoff[3] + swz0];
            if (pf) STG(pB, 128, t2, 24576);  // B-hi buf0
            FBAR;
            __builtin_amdgcn_s_setprio(1); MF16(0, a0, a1, a2, a3) __builtin_amdgcn_s_setprio(0);
            FBAR;
        }
        // ---- ph6: buf1, ksub0, m4-7
        {
            short8 a4 = *(const short8*)&lds[32768 + aoff[4] + swz0];
            short8 a5 = *(const short8*)&lds[32768 + aoff[5] + swz0];
            short8 a6 = *(const short8*)&lds[32768 + aoff[6] + swz0];
            short8 a7 = *(const short8*)&lds[32768 + aoff[7] + swz0];
            if (pf) STG(pA, 0, t2, 0);        // A-lo buf0
            FBAR;
            __builtin_amdgcn_s_setprio(1); MF16(4, a4, a5, a6, a7) __builtin_amdgcn_s_setprio(0);
            FBAR;
        }
        // ---- ph7: buf1, ksub1, m0-3 (reads B + A)
        bq0 = *(const short8*)&lds[32768 + boff[0] + swz1];
        bq1 = *(const short8*)&lds[32768 + boff[1] + swz1];
        bq2 = *(const short8*)&lds[32768 + boff[2] + swz1];
        bq3 = *(const short8*)&lds[32768 + boff[3] + swz1];
        {
            short8 a0 = *(const short8*)&lds[32768 + aoff[0] + swz1];
            short8 a1 = *(const short8*)&lds[32768 + aoff[1] + swz1];
            short8 a2 = *(const short8*)&lds[32768 + aoff[2] + swz1];
            short8 a3 = *(const short8*)&lds[32768 + aoff[3] + swz1];
            if (pf) STG(pA, 128, t2, 8192);   // A-hi buf0
            FBAR;
            __builtin_amdgcn_s_setprio(1); MF16(0, a0, a1, a2, a3) __builtin_amdgcn_s_setprio(0);
            FBAR;
        }
        // ---- ph8: buf1, ksub1, m4-7  + counted vmcnt
        {
            short8 a4 = *(const short8*)&lds[32768 + aoff[4] + swz1];
            short8 a5 = *(const short8*)&lds[32768 + aoff[5] + swz1];
            short8 a6 = *(const short8*)&lds[32768 + aoff[6] + swz1];
            short8 a7 = *(const short8*)&lds[32768 + aoff[7] + swz1];
            if (pf) STG(pB, 0, t3, 49152);    // B-lo buf1
            FBAR;
            __builtin_amdgcn_s_setprio(1); MF16(4, a4, a5, a6, a7) __builtin_amdgcn_s_setprio(0);
            if (pf) { asm volatile("s_waitcnt vmcnt(2)" ::: "memory"); }
            FBAR;
        }
    }
#undef STG
#undef FBAR
#undef MF16

    // ---------------- epilogue (swapped layout: row = rbase+lr, cols j-quad)
    if (EPI == 0) {
#pragma unroll
        for (int n = 0; n < 4; ++n) {
            int cbase = n0 + wn * 64 + n * 16 + kq * 4;
            float4 bv4 = *(const float4*)&bias[cbase];
#pragma unroll
            for (int m = 0; m < 8; ++m) {
                int row = m0 + wm * 128 + m * 16 + lr;
                ushort4 pk;
                pk.x = f2bf(fmaxf(acc[m][n][0] + bv4.x, 0.0f));
                pk.y = f2bf(fmaxf(acc[m][n][1] + bv4.y, 0.0f));
                pk.z = f2bf(fmaxf(acc[m][n][2] + bv4.z, 0.0f));
                pk.w = f2bf(fmaxf(acc[m][n][3] + bv4.w, 0.0f));
                *(ushort4*)(Y + (size_t)row * N + cbase) = pk;
            }
        }
    } else {
        float4 bv4[4], w34[4];
#pragma unroll
        for (int n = 0; n < 4; ++n) {
            int cbase = n0 + wn * 64 + n * 16 + kq * 4;
            bv4[n] = *(const float4*)&bias[cbase];
            w34[n] = *(const float4*)&w3[cbase];
        }
#pragma unroll
        for (int m = 0; m < 8; ++m) {
            float s = 0.0f;
#pragma unroll
            for (int n = 0; n < 4; ++n) {
                s += fmaxf(acc[m][n][0] + bv4[n].x, 0.0f) * w34[n].x;
                s += fmaxf(acc[m][n][1] + bv4[n].y, 0.0f) * w34[n].y;
                s += fmaxf(acc[m][n][2] + bv4[n].z, 0.0f) * w34[n].z;
                s += fmaxf(acc[m][n][3] + bv4[n].w, 0.0f) * w34[n].w;
            }
            s += __shfl_xor(s, 16, 64);
            s += __shfl_xor(s, 32, 64);
            if (kq == 0)
                atomicAdd(&logits[m0 + wm * 128 + m * 16 + lr], s);
        }
    }
}

// ---------------------------------------------------------------- logits = b3
__global__ void k_init_logits(float* __restrict__ logits, const float* __restrict__ b3, int n)
{
    int i = blockIdx.x * 256 + threadIdx.x;
    if (i < n) logits[i] = b3[0];
}

// --------------------------------------------- NMS + per-chunk top-50
__global__ __launch_bounds__(256) void k_nms_topk(
    const float* __restrict__ jloc, unsigned long long* __restrict__ cand)
{
    __shared__ unsigned long long sk[256];
    const int t = threadIdx.x;
    const int idx = blockIdx.x * 256 + t;      // 64 chunks x 2 rows
    const int y = idx >> 7, x = idx & 127;
    float cv = jloc[idx];
    float m = cv;
    for (int dy = -1; dy <= 1; ++dy) {
        int yy = y + dy;
        if (yy < 0 || yy > 127) continue;
        for (int dx = -1; dx <= 1; ++dx) {
            int xx = x + dx;
            if (xx < 0 || xx > 127) continue;
            m = fmaxf(m, jloc[(yy << 7) + xx]);
        }
    }
    float nv = (cv == m) ? cv : 0.0f;
    unsigned vb = __builtin_bit_cast(unsigned, nv);
    sk[t] = ((unsigned long long)vb << 32) | (unsigned)(0xFFFFFFFFu - idx);
    __syncthreads();
    for (int k = 2; k <= 256; k <<= 1) {
        for (int j = k >> 1; j >= 1; j >>= 1) {
            int ixj = t ^ j;
            if (ixj > t) {
                unsigned long long a = sk[t], b = sk[ixj];
                bool up = ((t & k) == 0);
                if (up ? (a < b) : (a > b)) { sk[t] = b; sk[ixj] = a; }
            }
            __syncthreads();
        }
    }
    if (t < 64) cand[blockIdx.x * 64 + t] = (t < 50) ? sk[t] : 0ull;
}

// --------------------------------------------- merge 64x50 -> top-50 + junctions
__global__ __launch_bounds__(1024) void k_topk_final(
    const unsigned long long* __restrict__ cand,
    const float* __restrict__ joff, float* __restrict__ outj)
{
    __shared__ unsigned long long sk[4096];
    const int t = threadIdx.x;
#pragma unroll
    for (int e = 0; e < 4; ++e) sk[t + (e << 10)] = cand[t + (e << 10)];
    __syncthreads();
    for (int k = 2; k <= 4096; k <<= 1) {
        for (int j = k >> 1; j >= 1; j >>= 1) {
#pragma unroll
            for (int e = 0; e < 4; ++e) {
                int i = t + (e << 10);
                int ixj = i ^ j;
                if (ixj > i) {
                    unsigned long long a = sk[i], b = sk[ixj];
                    bool up = ((i & k) == 0);
                    if (up ? (a < b) : (a > b)) { sk[i] = b; sk[ixj] = a; }
                }
            }
            __syncthreads();
        }
    }
    if (t < 50) {
        unsigned long long kk = sk[t];
        unsigned idx = 0xFFFFFFFFu - (unsigned)(kk & 0xFFFFFFFFull);
        float val = __builtin_bit_cast(float, (unsigned)(kk >> 32));
        int y = idx >> 7, x = idx & 127;
        outj[2 * t]     = (float)x + joff[idx]      + 0.5f;
        outj[2 * t + 1] = (float)y + joff[HW + idx] + 0.5f;
        outj[100 + t]   = val;
    }
}

// ---------------------------------------------------------------- launch
extern "C" void kernel_launch(void* const* d_in, const int* in_sizes, int n_in,
                              void* d_out, int out_size, void* d_ws, size_t ws_size,
                              hipStream_t stream) {
    const float* md   = (const float*)d_in[0];
    const float* dis  = (const float*)d_in[1];
    const float* res  = (const float*)d_in[2];
    const float* jloc = (const float*)d_in[3];
    const float* joff = (const float*)d_in[4];
    const float* feats= (const float*)d_in[5];
    const float* W1   = (const float*)d_in[6];
    const float* b1   = (const float*)d_in[7];
    const float* W2   = (const float*)d_in[8];
    const float* b2   = (const float*)d_in[9];
    const float* W3   = (const float*)d_in[10];
    const float* b3   = (const float*)d_in[11];
    float* out = (float*)d_out;

    char* ws = (char*)d_ws;
    size_t off = 0;
    auto alloc = [&](size_t bytes) {
        void* p = ws + off;
        off = (off + bytes + 255) & ~(size_t)255;
        return p;
    };
    float*  lines = (float*) alloc((size_t)NL * 4 * sizeof(float));
    ushort* ft    = (ushort*)alloc((size_t)HW * CC * 2);
    ushort* W1b   = (ushort*)alloc((size_t)1024 * 1024 * 2);
    ushort* W2b   = (ushort*)alloc((size_t)1024 * 1024 * 2);
    ushort* X     = (ushort*)alloc((size_t)NL * 1024 * 2);
    ushort* Y1    = (ushort*)alloc((size_t)NL * 1024 * 2);
    unsigned long long* cand = (unsigned long long*)alloc(4096 * 8);

    k_lines<<<NL / 256, 256, 0, stream>>>(md, dis, res, lines);
    k_transpose<<<dim3(CC / 32, HW / 32), dim3(32, 8), 0, stream>>>(feats, ft);
    k_cvt<<<(1024 * 1024) / 256, 256, 0, stream>>>(W1, W2, W1b, W2b, 1024 * 1024);
    k_pool<<<NL / 8, 128, 0, stream>>>(ft, lines, X);

    int ngrid = (NL / 256) * (1024 / 256);   // 768, divisible by 8
    k_gemm2<0><<<ngrid, 512, 0, stream>>>(X, W1b, b1, Y1, nullptr, nullptr, NL, 1024, 1024);
    k_init_logits<<<NL / 256, 256, 0, stream>>>(out, b3, NL);
    k_gemm2<1><<<ngrid, 512, 0, stream>>>(Y1, W2b, b2, nullptr, W3, out, NL, 1024, 1024);

    k_nms_topk<<<64, 256, 0, stream>>>(jloc, cand);
    k_topk_final<<<1, 1024, 0, stream>>>(cand, joff, out + NL);
}

// Round 11
// 350.363 us; speedup vs baseline: 1.0603x; 1.0070x over previous
//
#include <hip/hip_runtime.h>
#include <hip/hip_bf16.h>
#include <math.h>

#define HH 128
#define WW 128
#define HW 16384
#define NL 49152        // 3 * H * W lines
#define CC 128
#define NPTS0 32
#define NPTS1 8
#define PI_F 3.14159265358979323846f

typedef __attribute__((ext_vector_type(8))) short short8;
typedef __attribute__((ext_vector_type(4))) float f32x4;

__device__ __forceinline__ ushort f2bf(float f) {
    unsigned u = __builtin_bit_cast(unsigned, f);
    unsigned rounding = 0x7FFFu + ((u >> 16) & 1u);
    return (ushort)((u + rounding) >> 16);
}

__device__ __forceinline__ void gload_lds16(const void* gsrc, void* ldst) {
    __builtin_amdgcn_global_load_lds(
        (const __attribute__((address_space(1))) unsigned int*)gsrc,
        (__attribute__((address_space(3))) unsigned int*)ldst,
        16, 0, 0);
}

__device__ __forceinline__ void unpk8(uint4 d, float* f) {
    f[0] = __builtin_bit_cast(float, d.x << 16);
    f[1] = __builtin_bit_cast(float, d.x & 0xFFFF0000u);
    f[2] = __builtin_bit_cast(float, d.y << 16);
    f[3] = __builtin_bit_cast(float, d.y & 0xFFFF0000u);
    f[4] = __builtin_bit_cast(float, d.z << 16);
    f[5] = __builtin_bit_cast(float, d.z & 0xFFFF0000u);
    f[6] = __builtin_bit_cast(float, d.w << 16);
    f[7] = __builtin_bit_cast(float, d.w & 0xFFFF0000u);
}

// ---------------------------------------------------------------- lines
__global__ __launch_bounds__(256) void k_lines(
    const float* __restrict__ md, const float* __restrict__ dis,
    const float* __restrict__ res, float* __restrict__ lines)
{
    int g = blockIdx.x * 256 + threadIdx.x;
    if (g >= NL) return;
    int s = g / HW;              // 0,1,2 -> scale -1,0,1
    int pix = g - s * HW;
    float sf = (float)(s - 1);
    int y = pix >> 7, x = pix & 127;

    float md0 = md[pix], md1 = md[HW + pix], md2 = md[2 * HW + pix];
    float d = (dis[pix] + sf * res[pix]) * 5.0f;

    float md_ = (md0 - 0.5f) * (2.0f * PI_F);
    float st_ = md1 * (0.5f * PI_F);
    float ed_ = -md2 * (0.5f * PI_F);
    float cs_md = cosf(md_), ss_md = sinf(md_);
    float cs_st = fmaxf(cosf(st_), 0.001f);
    float ss_st = fmaxf(sinf(st_), 0.001f);
    float cs_ed = fmaxf(cosf(ed_), 0.001f);
    float ss_ed = fminf(sinf(ed_), -0.001f);
    float y_st = ss_st / cs_st;
    float y_ed = ss_ed / cs_ed;
    float x_st = (cs_md - ss_md * y_st) * d;
    float y_s  = (ss_md + cs_md * y_st) * d;
    float x_ed = (cs_md - ss_md * y_ed) * d;
    float y_e  = (ss_md + cs_md * y_ed) * d;

    float4 o;
    o.x = fminf(fmaxf(x_st + (float)x, 0.0f), 127.0f);
    o.y = fminf(fmaxf(y_s  + (float)y, 0.0f), 127.0f);
    o.z = fminf(fmaxf(x_ed + (float)x, 0.0f), 127.0f);
    o.w = fminf(fmaxf(y_e  + (float)y, 0.0f), 127.0f);
    ((float4*)lines)[g] = o;
}

// ---------------------------------- feats (C,HW) f32 -> (HW,C) bf16
__global__ void k_transpose(const float* __restrict__ in, ushort* __restrict__ out)
{
    __shared__ float tile[32][33];
    int cb = blockIdx.x;   // over C/32
    int pb = blockIdx.y;   // over HW/32
    int tx = threadIdx.x, ty = threadIdx.y;
#pragma unroll
    for (int j = 0; j < 32; j += 8)
        tile[ty + j][tx] = in[(size_t)(cb * 32 + ty + j) * HW + pb * 32 + tx];
    __syncthreads();
#pragma unroll
    for (int j = 0; j < 32; j += 8)
        out[(size_t)(pb * 32 + ty + j) * CC + cb * 32 + tx] = f2bf(tile[tx][ty + j]);
}

// ---------------------------------------------------------------- W -> bf16
__global__ void k_cvt(const float* __restrict__ a, const float* __restrict__ b,
                      ushort* __restrict__ oa, ushort* __restrict__ ob, int n)
{
    int i = blockIdx.x * 256 + threadIdx.x;
    if (i < n) { oa[i] = f2bf(a[i]); ob[i] = f2bf(b[i]); }
}

// ---------------------------------------------------------------- pooling
// block = 128 threads = 8 lines x 16 channel-groups-of-8.
// launch_bounds(128,2): VGPR cap 256 so m[8][8] + in-flight uint4s stay in
// registers (the (128,4) build chose VGPR=64 and spilled ~146 MB/launch).
__global__ __launch_bounds__(128, 2) void k_pool(
    const ushort* __restrict__ ft, const float* __restrict__ lines,
    ushort* __restrict__ X)
{
    __shared__ __align__(16) unsigned smeta[2048];   // 8 lines * 32 samples * 8 dwords
    const int t = threadIdx.x;
    const int l_loc = t >> 4, c8 = t & 15;
    const int gl0 = blockIdx.x * 8;

    // ---- phase A: per-(line,sample) meta, computed exactly once (2/thread)
#pragma unroll
    for (int e = 0; e < 2; ++e) {
        int s = t + e * 128;
        int ml = s >> 5, sp = s & 31;
        float4 L = ((const float4*)lines)[gl0 + ml];
        float tf = (float)sp * (1.0f / 31.0f);
        float omt = 1.0f - tf;
        float px = L.x * tf + L.z * omt - 0.5f;
        float py = L.y * tf + L.w * omt - 0.5f;
        float px0 = fminf(fmaxf(floorf(px), 0.0f), 127.0f);
        float py0 = fminf(fmaxf(floorf(py), 0.0f), 127.0f);
        float px1 = fminf(px0 + 1.0f, 127.0f);
        float py1 = fminf(py0 + 1.0f, 127.0f);
        int ix0 = (int)px0, iy0 = (int)py0, ix1 = (int)px1, iy1 = (int)py1;
        float4 wv;
        wv.x = (py1 - py) * (px1 - px);   // w00 (y0,x0)
        wv.y = (py  - py0) * (px1 - px);  // w10 (y1,x0)
        wv.z = (py1 - py) * (px  - px0);  // w01 (y0,x1)
        wv.w = (py  - py0) * (px  - px0); // w11 (y1,x1)
        int o00 = (iy0 * WW + ix0) * (CC * 2);
        int dx  = (ix1 - ix0) * (CC * 2);
        int dy  = (iy1 - iy0) * (WW * CC * 2);
        int4 ov;
        ov.x = o00;            // (y0,x0)
        ov.y = o00 + dy;       // (y1,x0)
        ov.z = o00 + dx;       // (y0,x1)
        ov.w = o00 + dy + dx;  // (y1,x1)
        *(float4*)&smeta[s * 8]     = wv;
        *(int4*)  &smeta[s * 8 + 4] = ov;
    }
    __syncthreads();

    // ---- phase B: gather (16B) + bilinear + max-pool
    const unsigned coff = (unsigned)(c8 * 16);
    const char* fbase = (const char*)ft;
    float m[8][8];
#pragma unroll
    for (int ch = 0; ch < 8; ++ch)
#pragma unroll
        for (int g = 0; g < 8; ++g) m[ch][g] = -INFINITY;

#pragma unroll
    for (int g = 0; g < 8; ++g) {
#pragma unroll
        for (int j = 0; j < 4; ++j) {
            const unsigned* mp = &smeta[(l_loc * 32 + g * 4 + j) * 8];
            float4 wv = *(const float4*)mp;
            int4  ov = *(const int4*)(mp + 4);
            uint4 d00 = *(const uint4*)(fbase + ((unsigned)ov.x + coff));
            uint4 d10 = *(const uint4*)(fbase + ((unsigned)ov.y + coff));
            uint4 d01 = *(const uint4*)(fbase + ((unsigned)ov.z + coff));
            uint4 d11 = *(const uint4*)(fbase + ((unsigned)ov.w + coff));
            float f00[8], f10[8], f01[8], f11[8];
            unpk8(d00, f00); unpk8(d10, f10); unpk8(d01, f01); unpk8(d11, f11);
#pragma unroll
            for (int ch = 0; ch < 8; ++ch) {
                float v = f00[ch] * wv.x + f10[ch] * wv.y
                        + f01[ch] * wv.z + f11[ch] * wv.w;
                m[ch][g] = fmaxf(m[ch][g], v);
            }
        }
    }

    ushort* Xp = X + (size_t)(gl0 + l_loc) * 1024 + c8 * 64;
#pragma unroll
    for (int ch = 0; ch < 8; ++ch) {
        short8 pk;
#pragma unroll
        for (int g = 0; g < 8; ++g) pk[g] = (short)f2bf(m[ch][g]);
        *(short8*)(Xp + ch * 8) = pk;
    }
}

// ---------------------------------------------------------------- GEMM 256x256
// 8-phase deep pipeline (m201 template): BK=64, 2 LDS buffers, per phase
// {ds_read subtile || stage 1 half-tile} -> barrier -> 16 MFMA -> barrier,
// counted vmcnt(2) only at phases 4 & 8. Row-XOR granule swizzle both sides.
// Block mapping: consecutive swz share the A-panel (m_blk = swz / nbn) so the
// nbn=4 sharers are co-resident on one XCD -> A read once into that L2.
#define NIT 8            // iterations; each covers 2 K-tiles of 64 (K=1024)
template<int EPI>
__global__ __launch_bounds__(512, 1) void k_gemm2(
    const ushort* __restrict__ A, const ushort* __restrict__ B,
    const float* __restrict__ bias, ushort* __restrict__ Y,
    const float* __restrict__ w3, float* __restrict__ logits,
    int M, int N, int K)
{
    __shared__ __align__(16) ushort lds[65536];
    const int tid = threadIdx.x;
    const int w = tid >> 6, l = tid & 63;
    const int lr = l & 15, kq = l >> 4;
    const int wm = w >> 2, wn = w & 3;

    // T1: bijective XCD swizzle (gridDim.x % 8 == 0)
    const int nwg = gridDim.x;
    const int cpx = nwg >> 3;
    const int swzb = (blockIdx.x & 7) * cpx + (blockIdx.x >> 3);
    const int nbn = N >> 8;
    const int m_blk = swzb / nbn;      // consecutive swz share A-panel
    const int n_blk = swzb % nbn;
    const int m0 = m_blk << 8, n0 = n_blk << 8;

    const ushort* pA = A + (size_t)m0 * K;
    const ushort* pB = B + (size_t)n0 * K;

    // staging: thread covers rows rS and rS+64 of a 128-row half-tile,
    // granule position tid&7; source granule inverse-swizzled.
    const int rS = tid >> 3;
    const int gS = (tid & 7) ^ (rS & 7);

#define STG(gp, rowoff, kt, regbase) { \
    gload_lds16((gp) + (size_t)((rowoff) + rS) * K + (kt) * 64 + gS * 8, \
                &lds[(regbase) + tid * 8]); \
    gload_lds16((gp) + (size_t)((rowoff) + 64 + rS) * K + (kt) * 64 + gS * 8, \
                &lds[(regbase) + 4096 + tid * 8]); }

#define FBAR { __builtin_amdgcn_sched_barrier(0); __builtin_amdgcn_s_barrier(); \
               __builtin_amdgcn_sched_barrier(0); }

    // ds_read offsets (ushort units); swizzled granule per k-sub
    const int swz0 = ((kq) ^ (lr & 7)) * 8;
    const int swz1 = ((4 + kq) ^ (lr & 7)) * 8;
    int aoff[8], boff[4];
#pragma unroll
    for (int m = 0; m < 8; ++m) aoff[m] = (wm * 128 + m * 16 + lr) * 64;
#pragma unroll
    for (int n = 0; n < 4; ++n) boff[n] = 16384 + (wn * 64 + n * 16 + lr) * 64;

    f32x4 acc[8][4] = {};
    short8 bq0, bq1, bq2, bq3;

#define MF16(MLO, A0, A1, A2, A3) \
    acc[MLO+0][0] = __builtin_amdgcn_mfma_f32_16x16x32_bf16(bq0, A0, acc[MLO+0][0], 0, 0, 0); \
    acc[MLO+0][1] = __builtin_amdgcn_mfma_f32_16x16x32_bf16(bq1, A0, acc[MLO+0][1], 0, 0, 0); \
    acc[MLO+0][2] = __builtin_amdgcn_mfma_f32_16x16x32_bf16(bq2, A0, acc[MLO+0][2], 0, 0, 0); \
    acc[MLO+0][3] = __builtin_amdgcn_mfma_f32_16x16x32_bf16(bq3, A0, acc[MLO+0][3], 0, 0, 0); \
    acc[MLO+1][0] = __builtin_amdgcn_mfma_f32_16x16x32_bf16(bq0, A1, acc[MLO+1][0], 0, 0, 0); \
    acc[MLO+1][1] = __builtin_amdgcn_mfma_f32_16x16x32_bf16(bq1, A1, acc[MLO+1][1], 0, 0, 0); \
    acc[MLO+1][2] = __builtin_amdgcn_mfma_f32_16x16x32_bf16(bq2, A1, acc[MLO+1][2], 0, 0, 0); \
    acc[MLO+1][3] = __builtin_amdgcn_mfma_f32_16x16x32_bf16(bq3, A1, acc[MLO+1][3], 0, 0, 0); \
    acc[MLO+2][0] = __builtin_amdgcn_mfma_f32_16x16x32_bf16(bq0, A2, acc[MLO+2][0], 0, 0, 0); \
    acc[MLO+2][1] = __builtin_amdgcn_mfma_f32_16x16x32_bf16(bq1, A2, acc[MLO+2][1], 0, 0, 0); \
    acc[MLO+2][2] = __builtin_amdgcn_mfma_f32_16x16x32_bf16(bq2, A2, acc[MLO+2][2], 0, 0, 0); \
    acc[MLO+2][3] = __builtin_amdgcn_mfma_f32_16x16x32_bf16(bq3, A2, acc[MLO+2][3], 0, 0, 0); \
    acc[MLO+3][0] = __builtin_amdgcn_mfma_f32_16x16x32_bf16(bq0, A3, acc[MLO+3][0], 0, 0, 0); \
    acc[MLO+3][1] = __builtin_amdgcn_mfma_f32_16x16x32_bf16(bq1, A3, acc[MLO+3][1], 0, 0, 0); \
    acc[MLO+3][2] = __builtin_amdgcn_mfma_f32_16x16x32_bf16(bq2, A3, acc[MLO+3][2], 0, 0, 0); \
    acc[MLO+3][3] = __builtin_amdgcn_mfma_f32_16x16x32_bf16(bq3, A3, acc[MLO+3][3], 0, 0, 0);

    // prologue: tile0 fully into buf0, tile1's B-lo into buf1
    STG(pA, 0,   0, 0);      // A-lo buf0
    STG(pA, 128, 0, 8192);   // A-hi buf0
    STG(pB, 0,   0, 16384);  // B-lo buf0
    STG(pB, 128, 0, 24576);  // B-hi buf0
    STG(pB, 0,   1, 49152);  // B-lo buf1
    asm volatile("s_waitcnt vmcnt(2)" ::: "memory");
    FBAR;

    for (int i = 0; i < NIT; ++i) {
        const int t1 = 2 * i + 1, t2 = 2 * i + 2, t3 = 2 * i + 3;
        const bool pf = (i < NIT - 1);

        // ---- ph1: buf0, ksub0, m0-3 (reads B + A)
        bq0 = *(const short8*)&lds[boff[0] + swz0];
        bq1 = *(const short8*)&lds[boff[1] + swz0];
        bq2 = *(const short8*)&lds[boff[2] + swz0];
        bq3 = *(const short8*)&lds[boff[3] + swz0];
        {
            short8 a0 = *(const short8*)&lds[aoff[0] + swz0];
            short8 a1 = *(const short8*)&lds[aoff[1] + swz0];
            short8 a2 = *(const short8*)&lds[aoff[2] + swz0];
            short8 a3 = *(const short8*)&lds[aoff[3] + swz0];
            STG(pB, 128, t1, 57344);   // B-hi buf1
            FBAR;
            __builtin_amdgcn_s_setprio(1); MF16(0, a0, a1, a2, a3) __builtin_amdgcn_s_setprio(0);
            FBAR;
        }
        // ---- ph2: buf0, ksub0, m4-7
        {
            short8 a4 = *(const short8*)&lds[aoff[4] + swz0];
            short8 a5 = *(const short8*)&lds[aoff[5] + swz0];
            short8 a6 = *(const short8*)&lds[aoff[6] + swz0];
            short8 a7 = *(const short8*)&lds[aoff[7] + swz0];
            STG(pA, 0, t1, 32768);     // A-lo buf1
            FBAR;
            __builtin_amdgcn_s_setprio(1); MF16(4, a4, a5, a6, a7) __builtin_amdgcn_s_setprio(0);
            FBAR;
        }
        // ---- ph3: buf0, ksub1, m0-3 (reads B + A)
        bq0 = *(const short8*)&lds[boff[0] + swz1];
        bq1 = *(const short8*)&lds[boff[1] + swz1];
        bq2 = *(const short8*)&lds[boff[2] + swz1];
        bq3 = *(const short8*)&lds[boff[3] + swz1];
        {
            short8 a0 = *(const short8*)&lds[aoff[0] + swz1];
            short8 a1 = *(const short8*)&lds[aoff[1] + swz1];
            short8 a2 = *(const short8*)&lds[aoff[2] + swz1];
            short8 a3 = *(const short8*)&lds[aoff[3] + swz1];
            STG(pA, 128, t1, 40960);   // A-hi buf1
            FBAR;
            __builtin_amdgcn_s_setprio(1); MF16(0, a0, a1, a2, a3) __builtin_amdgcn_s_setprio(0);
            FBAR;
        }
        // ---- ph4: buf0, ksub1, m4-7  + counted vmcnt
        {
            short8 a4 = *(const short8*)&lds[aoff[4] + swz1];
            short8 a5 = *(const short8*)&lds[aoff[5] + swz1];
            short8 a6 = *(const short8*)&lds[aoff[6] + swz1];
            short8 a7 = *(const short8*)&lds[aoff[7] + swz1];
            if (pf) STG(pB, 0, t2, 16384);   // B-lo buf0
            FBAR;
            __builtin_amdgcn_s_setprio(1); MF16(4, a4, a5, a6, a7) __builtin_amdgcn_s_setprio(0);
            if (pf) { asm volatile("s_waitcnt vmcnt(2)" ::: "memory"); }
            else    { asm volatile("s_waitcnt vmcnt(0)" ::: "memory"); }
            FBAR;
        }
        // ---- ph5: buf1, ksub0, m0-3 (reads B + A)
        bq0 = *(const short8*)&lds[32768 + boff[0] + swz0];
        bq1 = *(const short8*)&lds[32768 + boff[1] + swz0];
        bq2 = *(const short8*)&lds[32768 + boff[2] + swz0];
        bq3 = *(const short8*)&lds[32768 + boff[3] + swz0];
        {
            short8 a0 = *(const short8*)&lds[32768 + aoff[0] + swz0];
            short8 a1 = *(const short8*)&lds[32768 + aoff[1] + swz0];
            short8 a2 = *(const short8*)&lds[32768 + aoff[2] + swz0];
            short8 a3 = *(const short8*)&lds[32768 + aoff[3] + swz0];
            if (pf) STG(pB, 128, t2, 24576);  // B-hi buf0
            FBAR;
            __builtin_amdgcn_s_setprio(1); MF16(0, a0, a1, a2, a3) __builtin_amdgcn_s_setprio(0);
            FBAR;
        }
        // ---- ph6: buf1, ksub0, m4-7
        {
            short8 a4 = *(const short8*)&lds[32768 + aoff[4] + swz0];
            short8 a5 = *(const short8*)&lds[32768 + aoff[5] + swz0];
            short8 a6 = *(const short8*)&lds[32768 + aoff[6] + swz0];
            short8 a7 = *(const short8*)&lds[32768 + aoff[7] + swz0];
            if (pf) STG(pA, 0, t2, 0);        // A-lo buf0
            FBAR;
            __builtin_amdgcn_s_setprio(1); MF16(4, a4, a5, a6, a7) __builtin_amdgcn_s_setprio(0);
            FBAR;
        }
        // ---- ph7: buf1, ksub1, m0-3 (reads B + A)
        bq0 = *(const short8*)&lds[32768 + boff[0] + swz1];
        bq1 = *(const short8*)&lds[32768 + boff[1] + swz1];
        bq2 = *(const short8*)&lds[32768 + boff[2] + swz1];
        bq3 = *(const short8*)&lds[32768 + boff[3] + swz1];
        {
            short8 a0 = *(const short8*)&lds[32768 + aoff[0] + swz1];
            short8 a1 = *(const short8*)&lds[32768 + aoff[1] + swz1];
            short8 a2 = *(const short8*)&lds[32768 + aoff[2] + swz1];
            short8 a3 = *(const short8*)&lds[32768 + aoff[3] + swz1];
            if (pf) STG(pA, 128, t2, 8192);   // A-hi buf0
            FBAR;
            __builtin_amdgcn_s_setprio(1); MF16(0, a0, a1, a2, a3) __builtin_amdgcn_s_setprio(0);
            FBAR;
        }
        // ---- ph8: buf1, ksub1, m4-7  + counted vmcnt
        {
            short8 a4 = *(const short8*)&lds[32768 + aoff[4] + swz1];
            short8 a5 = *(const short8*)&lds[32768 + aoff[5] + swz1];
            short8 a6 = *(const short8*)&lds[32768 + aoff[6] + swz1];
            short8 a7 = *(const short8*)&lds[32768 + aoff[7] + swz1];
            if (pf) STG(pB, 0, t3, 49152);    // B-lo buf1
            FBAR;
            __builtin_amdgcn_s_setprio(1); MF16(4, a4, a5, a6, a7) __builtin_amdgcn_s_setprio(0);
            if (pf) { asm volatile("s_waitcnt vmcnt(2)" ::: "memory"); }
            FBAR;
        }
    }
#undef STG
#undef FBAR
#undef MF16

    // ---------------- epilogue (swapped layout: row = rbase+lr, cols j-quad)
    if (EPI == 0) {
#pragma unroll
        for (int n = 0; n < 4; ++n) {
            int cbase = n0 + wn * 64 + n * 16 + kq * 4;
            float4 bv4 = *(const float4*)&bias[cbase];
#pragma unroll
            for (int m = 0; m < 8; ++m) {
                int row = m0 + wm * 128 + m * 16 + lr;
                ushort4 pk;
                pk.x = f2bf(fmaxf(acc[m][n][0] + bv4.x, 0.0f));
                pk.y = f2bf(fmaxf(acc[m][n][1] + bv4.y, 0.0f));
                pk.z = f2bf(fmaxf(acc[m][n][2] + bv4.z, 0.0f));
                pk.w = f2bf(fmaxf(acc[m][n][3] + bv4.w, 0.0f));
                *(ushort4*)(Y + (size_t)row * N + cbase) = pk;
            }
        }
    } else {
        float4 bv4[4], w34[4];
#pragma unroll
        for (int n = 0; n < 4; ++n) {
            int cbase = n0 + wn * 64 + n * 16 + kq * 4;
            bv4[n] = *(const float4*)&bias[cbase];
            w34[n] = *(const float4*)&w3[cbase];
        }
#pragma unroll
        for (int m = 0; m < 8; ++m) {
            float s = 0.0f;
#pragma unroll
            for (int n = 0; n < 4; ++n) {
                s += fmaxf(acc[m][n][0] + bv4[n].x, 0.0f) * w34[n].x;
                s += fmaxf(acc[m][n][1] + bv4[n].y, 0.0f) * w34[n].y;
                s += fmaxf(acc[m][n][2] + bv4[n].z, 0.0f) * w34[n].z;
                s += fmaxf(acc[m][n][3] + bv4[n].w, 0.0f) * w34[n].w;
            }
            s += __shfl_xor(s, 16, 64);
            s += __shfl_xor(s, 32, 64);
            if (kq == 0)
                atomicAdd(&logits[m0 + wm * 128 + m * 16 + lr], s);
        }
    }
}

// ---------------------------------------------------------------- logits = b3
__global__ void k_init_logits(float* __restrict__ logits, const float* __restrict__ b3, int n)
{
    int i = blockIdx.x * 256 + threadIdx.x;
    if (i < n) logits[i] = b3[0];
}

// --------------------------------------------- NMS + per-chunk top-50
__global__ __launch_bounds__(256) void k_nms_topk(
    const float* __restrict__ jloc, unsigned long long* __restrict__ cand)
{
    __shared__ unsigned long long sk[256];
    const int t = threadIdx.x;
    const int idx = blockIdx.x * 256 + t;      // 64 chunks x 2 rows
    const int y = idx >> 7, x = idx & 127;
    float cv = jloc[idx];
    float m = cv;
    for (int dy = -1; dy <= 1; ++dy) {
        int yy = y + dy;
        if (yy < 0 || yy > 127) continue;
        for (int dx = -1; dx <= 1; ++dx) {
            int xx = x + dx;
            if (xx < 0 || xx > 127) continue;
            m = fmaxf(m, jloc[(yy << 7) + xx]);
        }
    }
    float nv = (cv == m) ? cv : 0.0f;
    unsigned vb = __builtin_bit_cast(unsigned, nv);
    sk[t] = ((unsigned long long)vb << 32) | (unsigned)(0xFFFFFFFFu - idx);
    __syncthreads();
    for (int k = 2; k <= 256; k <<= 1) {
        for (int j = k >> 1; j >= 1; j >>= 1) {
            int ixj = t ^ j;
            if (ixj > t) {
                unsigned long long a = sk[t], b = sk[ixj];
                bool up = ((t & k) == 0);
                if (up ? (a < b) : (a > b)) { sk[t] = b; sk[ixj] = a; }
            }
            __syncthreads();
        }
    }
    if (t < 64) cand[blockIdx.x * 64 + t] = (t < 50) ? sk[t] : 0ull;
}

// --------------------------------------------- merge 64x50 -> top-50 + junctions
__global__ __launch_bounds__(1024) void k_topk_final(
    const unsigned long long* __restrict__ cand,
    const float* __restrict__ joff, float* __restrict__ outj)
{
    __shared__ unsigned long long sk[4096];
    const int t = threadIdx.x;
#pragma unroll
    for (int e = 0; e < 4; ++e) sk[t + (e << 10)] = cand[t + (e << 10)];
    __syncthreads();
    for (int k = 2; k <= 4096; k <<= 1) {
        for (int j = k >> 1; j >= 1; j >>= 1) {
#pragma unroll
            for (int e = 0; e < 4; ++e) {
                int i = t + (e << 10);
                int ixj = i ^ j;
                if (ixj > i) {
                    unsigned long long a = sk[i], b = sk[ixj];
                    bool up = ((i & k) == 0);
                    if (up ? (a < b) : (a > b)) { sk[i] = b; sk[ixj] = a; }
                }
            }
            __syncthreads();
        }
    }
    if (t < 50) {
        unsigned long long kk = sk[t];
        unsigned idx = 0xFFFFFFFFu - (unsigned)(kk & 0xFFFFFFFFull);
        float val = __builtin_bit_cast(float, (unsigned)(kk >> 32));
        int y = idx >> 7, x = idx & 127;
        outj[2 * t]     = (float)x + joff[idx]      + 0.5f;
        outj[2 * t + 1] = (float)y + joff[HW + idx] + 0.5f;
        outj[100 + t]   = val;
    }
}

// ---------------------------------------------------------------- launch
extern "C" void kernel_launch(void* const* d_in, const int* in_sizes, int n_in,
                              void* d_out, int out_size, void* d_ws, size_t ws_size,
                              hipStream_t stream) {
    const float* md   = (const float*)d_in[0];
    const float* dis  = (const float*)d_in[1];
    const float* res  = (const float*)d_in[2];
    const float* jloc = (const float*)d_in[3];
    const float* joff = (const float*)d_in[4];
    const float* feats= (const float*)d_in[5];
    const float* W1   = (const float*)d_in[6];
    const float* b1   = (const float*)d_in[7];
    const float* W2   = (const float*)d_in[8];
    const float* b2   = (const float*)d_in[9];
    const float* W3   = (const float*)d_in[10];
    const float* b3   = (const float*)d_in[11];
    float* out = (float*)d_out;

    char* ws = (char*)d_ws;
    size_t off = 0;
    auto alloc = [&](size_t bytes) {
        void* p = ws + off;
        off = (off + bytes + 255) & ~(size_t)255;
        return p;
    };
    float*  lines = (float*) alloc((size_t)NL * 4 * sizeof(float));
    ushort* ft    = (ushort*)alloc((size_t)HW * CC * 2);
    ushort* W1b   = (ushort*)alloc((size_t)1024 * 1024 * 2);
    ushort* W2b   = (ushort*)alloc((size_t)1024 * 1024 * 2);
    ushort* X     = (ushort*)alloc((size_t)NL * 1024 * 2);
    ushort* Y1    = (ushort*)alloc((size_t)NL * 1024 * 2);
    unsigned long long* cand = (unsigned long long*)alloc(4096 * 8);

    k_lines<<<NL / 256, 256, 0, stream>>>(md, dis, res, lines);
    k_transpose<<<dim3(CC / 32, HW / 32), dim3(32, 8), 0, stream>>>(feats, ft);
    k_cvt<<<(1024 * 1024) / 256, 256, 0, stream>>>(W1, W2, W1b, W2b, 1024 * 1024);
    k_pool<<<NL / 8, 128, 0, stream>>>(ft, lines, X);

    int ngrid = (NL / 256) * (1024 / 256);   // 768, divisible by 8
    k_gemm2<0><<<ngrid, 512, 0, stream>>>(X, W1b, b1, Y1, nullptr, nullptr, NL, 1024, 1024);
    k_init_logits<<<NL / 256, 256, 0, stream>>>(out, b3, NL);
    k_gemm2<1><<<ngrid, 512, 0, stream>>>(Y1, W2b, b2, nullptr, W3, out, NL, 1024, 1024);

    k_nms_topk<<<64, 256, 0, stream>>>(jloc, cand);
    k_topk_final<<<1, 1024, 0, stream>>>(cand, joff, out + NL);
}